// Round 10
// baseline (240.978 us; speedup 1.0000x reference)
//
#include <hip/hip_runtime.h>

// Problem constants (B=4, T=S=1024, E=1024, CTX=768, H=16, DH=64)
#define NB 4
#define TT 1024
#define SS 1024
#define EE 1024
#define CCH 768
#define NH 16
#define DHH 64
#define EPSF 1e-5f
// SCALE = 1024 // (16**0.5) = 256.  Fold 1/256 * log2(e) into q so that
// exp(score/256) == exp2(q'.k) with a single v_exp_f32.
#define QSCALE (1.4426950408889634f / 256.0f)

typedef unsigned short u16;
typedef __attribute__((ext_vector_type(8))) short short8;       // MFMA A/B frag
typedef __attribute__((ext_vector_type(8))) unsigned short u16x8;
typedef __attribute__((ext_vector_type(4))) unsigned short u16x4;
typedef __attribute__((ext_vector_type(4))) float f32x4;        // MFMA C/D frag

__device__ __forceinline__ u16 f2bu(float f) {
    union { float f; unsigned u; } x; x.f = f;
    unsigned r = x.u + 0x7fffu + ((x.u >> 16) & 1u);
    return (u16)(r >> 16);
}
__device__ __forceinline__ float bu2f(u16 u) {
    union { unsigned u; float f; } x; x.u = ((unsigned)u) << 16; return x.f;
}

#if __has_builtin(__builtin_amdgcn_exp2f)
#define EXP2(x) __builtin_amdgcn_exp2f(x)
#else
#define EXP2(x) exp2f(x)
#endif

#define MFMA16(a, b, c) __builtin_amdgcn_mfma_f32_16x16x32_bf16((a), (b), (c), 0, 0, 0)

// ---------------------------------------------------------------------------
// Weight standardization (4 matrices) + mask scan, one dispatch.
// grid (1024, 5): y<4 -> WS rows; y==4, x<8 -> mask prefix/index/count.
// ---------------------------------------------------------------------------
__global__ __launch_bounds__(256) void ws_norm_scan(
    const float* __restrict__ qw, const float* __restrict__ kw,
    const float* __restrict__ vw, const float* __restrict__ ow,
    u16* __restrict__ wqn, u16* __restrict__ wkn,
    u16* __restrict__ wvn, u16* __restrict__ won,
    const int* __restrict__ mask, const int* __restrict__ mask_ctx,
    int* __restrict__ tIdx, int* __restrict__ sIdx,
    int* __restrict__ cntQ, int* __restrict__ cntK) {
    int tid = threadIdx.x;
    if (blockIdx.y == 4) {
        if (blockIdx.x >= 8) return;
        int which = blockIdx.x & 1, b = blockIdx.x >> 1;
        const int* m = (which ? mask_ctx : mask) + b * 1024;
        int* idx = (which ? sIdx : tIdx) + b * 1024;
        int* cnt = (which ? cntK : cntQ) + b;
        int base = tid * 4;
        int v[4]; int s = 0;
#pragma unroll
        for (int i = 0; i < 4; i++) { v[i] = m[base + i] ? 1 : 0; s += v[i]; }
        int lane = tid & 63, wid = tid >> 6;
        int inc = s;
#pragma unroll
        for (int off = 1; off < 64; off <<= 1) {
            int o = __shfl_up(inc, off);
            if (lane >= off) inc += o;
        }
        __shared__ int wtot[4];
        if (lane == 63) wtot[wid] = inc;
        __syncthreads();
        int woff = 0;
        for (int i = 0; i < wid; i++) woff += wtot[i];
        int p = woff + inc - s;
#pragma unroll
        for (int i = 0; i < 4; i++) {
            if (v[i]) idx[p] = base + i;
            p += v[i];
        }
        if (tid == 255) *cnt = p;
        return;
    }
    int mat = blockIdx.y;
    const float* w = mat == 0 ? qw : (mat == 1 ? kw : (mat == 2 ? vw : ow));
    u16* wn = mat == 0 ? wqn : (mat == 1 ? wkn : (mat == 2 ? wvn : won));
    int I = (mat == 1 || mat == 2) ? CCH : EE;
    int row = blockIdx.x;
    const float* wr = w + (size_t)row * I;
    float s = 0.f, s2 = 0.f;
    for (int i = tid; i < I; i += 256) { float v = wr[i]; s += v; s2 += v * v; }
#pragma unroll
    for (int off = 32; off > 0; off >>= 1) { s += __shfl_down(s, off); s2 += __shfl_down(s2, off); }
    __shared__ float sa[4], sb[4], smean, srstd;
    int wid = tid >> 6;
    if ((tid & 63) == 0) { sa[wid] = s; sb[wid] = s2; }
    __syncthreads();
    if (tid == 0) {
        float ts = sa[0] + sa[1] + sa[2] + sa[3];
        float ts2 = sb[0] + sb[1] + sb[2] + sb[3];
        float mean = ts / (float)I;
        float var = ts2 / (float)I - mean * mean;
        smean = mean; srstd = rsqrtf(var + EPSF);
    }
    __syncthreads();
    float mean = smean, r = srstd;
    u16* wo = wn + (size_t)row * I;
    for (int i = tid; i < I; i += 256) wo[i] = f2bu((wr[i] - mean) * r);
}

// ---------------------------------------------------------------------------
// Fused COMPACTING transpose: f32 [b][R][1024] -> bf16 [b][pos][R], keeping
// only unmasked l-columns (block computes its own mask prefix scan).
// grid (16, 16+12, NB): y<16 -> x/mask (R=1024), y>=16 -> ctx/mask_ctx (768).
// ---------------------------------------------------------------------------
__global__ __launch_bounds__(256) void transpose2_compact(
    const float* __restrict__ x, const float* __restrict__ ctx,
    const int* __restrict__ mask, const int* __restrict__ mask_ctx,
    u16* __restrict__ xc, u16* __restrict__ cc) {
    __shared__ float tile[64][65];
    __shared__ int spos[64], smask[64], wtot[4];
    int yy = blockIdx.y;
    int mat = yy < 16 ? 0 : 1;
    int r0 = (mat == 0 ? yy : yy - 16) * 64;
    int R = mat == 0 ? EE : CCH;
    const float* in = mat == 0 ? x : ctx;
    const int* m = (mat == 0 ? mask : mask_ctx) + (size_t)blockIdx.z * 1024;
    u16* out = mat == 0 ? xc : cc;
    int c0 = blockIdx.x * 64, b = blockIdx.z;
    const float* ip = in + (size_t)b * R * 1024;
    u16* op = out + (size_t)b * R * 1024;
    int tid = threadIdx.x;
#pragma unroll
    for (int mm = 0; mm < 16; mm++) {
        int id = tid + 256 * mm; int r = id >> 6, c = id & 63;
        tile[r][c] = ip[(size_t)(r0 + r) * 1024 + c0 + c];
    }
    int base = tid * 4;
    int v[4]; int s = 0;
#pragma unroll
    for (int i = 0; i < 4; i++) { v[i] = m[base + i] ? 1 : 0; s += v[i]; }
    int lane = tid & 63, wid = tid >> 6;
    int inc = s;
#pragma unroll
    for (int off = 1; off < 64; off <<= 1) {
        int o = __shfl_up(inc, off);
        if (lane >= off) inc += o;
    }
    if (lane == 63) wtot[wid] = inc;
    __syncthreads();
    int woff = 0;
    for (int i = 0; i < wid; i++) woff += wtot[i];
    int p = woff + inc - s;
#pragma unroll
    for (int i = 0; i < 4; i++) {
        int g = base + i;
        if (g >= c0 && g < c0 + 64) { spos[g - c0] = p; smask[g - c0] = v[i]; }
        p += v[i];
    }
    __syncthreads();
#pragma unroll
    for (int mm = 0; mm < 16; mm++) {
        int id = tid + 256 * mm; int rr = id >> 6, cc2 = id & 63;
        if (smask[rr])
            op[(size_t)spos[rr] * R + r0 + cc2] = f2bu(tile[cc2][rr]);
    }
}

// ---------------------------------------------------------------------------
// GEMM core: 64x64 tile, 4 waves; wave w owns cols w*16..w*16+15 over all
// 64 rows (4x1 16x16x32 frags). Prefetch distance 2 (I % 128 == 0).
// Doubles block-level parallelism vs the old 128x64 tile (latency-bound fix).
// ---------------------------------------------------------------------------
__device__ __forceinline__ void gemm_core64(
    const u16* __restrict__ A, const u16* __restrict__ Bp, int I,
    int o0, int l0, u16 (*at)[72], u16 (*bt)[72], f32x4 (&acc)[4]) {
    int tid = threadIdx.x;
    int w = tid >> 6, lane = tid & 63, quad = lane >> 4, l16 = lane & 15;
    int rA = tid >> 3, cA = (tid & 7) * 8;          // rows 0..31, 16B cols
    u16x8 ra[2][2], rb[2][2];
#pragma unroll
    for (int p = 0; p < 2; p++) {
        int kb = p * 64;
#pragma unroll
        for (int m = 0; m < 2; m++) {
            ra[p][m] = *(const u16x8*)&A[(size_t)(o0 + rA + 32 * m) * I + kb + cA];
            rb[p][m] = *(const u16x8*)&Bp[(size_t)(l0 + rA + 32 * m) * I + kb + cA];
        }
    }
    for (int k0 = 0; k0 < I; k0 += 128) {
#pragma unroll
        for (int half = 0; half < 2; half++) {
            __syncthreads();
#pragma unroll
            for (int m = 0; m < 2; m++) {
                *(u16x8*)&at[rA + 32 * m][cA] = ra[half][m];
                *(u16x8*)&bt[rA + 32 * m][cA] = rb[half][m];
            }
            __syncthreads();
            int kpre = k0 + half * 64 + 128;
            if (kpre < I) {
#pragma unroll
                for (int m = 0; m < 2; m++) {
                    ra[half][m] = *(const u16x8*)&A[(size_t)(o0 + rA + 32 * m) * I + kpre + cA];
                    rb[half][m] = *(const u16x8*)&Bp[(size_t)(l0 + rA + 32 * m) * I + kpre + cA];
                }
            }
#pragma unroll
            for (int ks = 0; ks < 64; ks += 32) {
                short8 bf = *(const short8*)&bt[w * 16 + l16][ks + quad * 8];
#pragma unroll
                for (int mt = 0; mt < 4; mt++) {
                    short8 af = *(const short8*)&at[mt * 16 + l16][ks + quad * 8];
                    acc[mt] = MFMA16(af, bf, acc[mt]);
                }
            }
        }
    }
}

// ---------------------------------------------------------------------------
// Fused q/k/v projections over COMPACT columns + per-head LN epilogue (q,k).
// 64x64 tiles: a 64-row o-tile = exactly 1 head; for fixed l one wave holds
// all 64 d values (16 local + shfl_xor 16/32). Blocks past the count exit.
// grid (16, 48, NB): mat = y>>4, o0 = (y&15)*64.
// ---------------------------------------------------------------------------
__global__ __launch_bounds__(256) void proj_qkv(
    const u16* __restrict__ wq, const u16* __restrict__ wk, const u16* __restrict__ wv,
    const u16* __restrict__ xc, const u16* __restrict__ cc,
    const float* __restrict__ qb, const float* __restrict__ kb, const float* __restrict__ vbi,
    const int* __restrict__ cntQ, const int* __restrict__ cntK,
    const float* __restrict__ gq, const float* __restrict__ bq,
    const float* __restrict__ gk, const float* __restrict__ bk,
    u16* __restrict__ qc, u16* __restrict__ kc, u16* __restrict__ yv) {
    int mat = blockIdx.y >> 4;
    int l0 = blockIdx.x * 64;
    int b = blockIdx.z;
    int limit = (mat == 0) ? cntQ[b] : cntK[b];
    if (l0 >= limit) return;
    __shared__ u16 at[64][72];
    __shared__ u16 bt[64][72];
    __shared__ float sg[64], sbe[64], sbias[64];
    int tid = threadIdx.x;
    int w = tid >> 6, lane = tid & 63, quad = lane >> 4, l16 = lane & 15;
    int o0 = (blockIdx.y & 15) * 64;
    const u16* A = mat == 0 ? wq : (mat == 1 ? wk : wv);
    const u16* BT = mat == 0 ? xc : cc;
    const float* bias = mat == 0 ? qb : (mat == 1 ? kb : vbi);
    int I = mat == 0 ? EE : CCH;
    if (tid < 64) {
        sbias[tid] = bias[o0 + tid];
        if (mat < 2) {
            sg[tid] = (mat == 0 ? gq : gk)[tid];
            sbe[tid] = (mat == 0 ? bq : bk)[tid];
        }
    }

    f32x4 acc[4] = {};
    gemm_core64(A, BT + (size_t)b * 1024 * I, I, o0, l0, at, bt, acc);

    int l = l0 + w * 16 + l16;
    if (mat < 2) {
        u16* outT = mat == 0 ? qc : kc;
        float scale = mat == 0 ? QSCALE : 1.0f;
        int bh = b * NH + (o0 >> 6);
        float vbuf[16];
        float s = 0.f;
#pragma unroll
        for (int mt = 0; mt < 4; mt++)
#pragma unroll
            for (int reg = 0; reg < 4; reg++) {
                float v = acc[mt][reg] + sbias[mt * 16 + quad * 4 + reg];
                vbuf[mt * 4 + reg] = v; s += v;
            }
        s += __shfl_xor(s, 16); s += __shfl_xor(s, 32);
        float mean = s * (1.f / 64);
        float s2 = 0.f;
#pragma unroll
        for (int i = 0; i < 16; i++) { float dv = vbuf[i] - mean; s2 += dv * dv; }
        s2 += __shfl_xor(s2, 16); s2 += __shfl_xor(s2, 32);
        float r = rsqrtf(s2 * (1.f / 64) + EPSF);
        if (l < limit) {
            u16* op = outT + ((size_t)bh * 1024 + l) * 64;
#pragma unroll
            for (int mt = 0; mt < 4; mt++) {
                u16x4 pk;
#pragma unroll
                for (int reg = 0; reg < 4; reg++) {
                    int d = mt * 16 + quad * 4 + reg;
                    pk[reg] = f2bu(((vbuf[mt * 4 + reg] - mean) * r * sg[d] + sbe[d]) * scale);
                }
                *(u16x4*)&op[mt * 16 + quad * 4] = pk;
            }
        }
    } else {
        if (l < limit) {
#pragma unroll
            for (int mt = 0; mt < 4; mt++)
#pragma unroll
                for (int reg = 0; reg < 4; reg++) {
                    int o = o0 + mt * 16 + quad * 4 + reg;
                    float v = acc[mt][reg] + sbias[mt * 16 + quad * 4 + reg];
                    yv[((size_t)b * EE + o) * 1024 + l] = f2bu(v);
                }
        }
    }
}

// ---------------------------------------------------------------------------
// Output projection (+mask, +f32 residual) -> f32, 64x64 tiles.
// grid (16, 16, NB) = 1024 blocks (~4/CU).
// ---------------------------------------------------------------------------
__global__ __launch_bounds__(256) void proj_o(
    const u16* __restrict__ won, const u16* __restrict__ aT,
    const float* __restrict__ obi, const int* __restrict__ mask,
    const float* __restrict__ x, float* __restrict__ out) {
    __shared__ u16 at[64][72];
    __shared__ u16 bt[64][72];
    __shared__ float sbias[64];
    int tid = threadIdx.x;
    int w = tid >> 6, lane = tid & 63, quad = lane >> 4, l16 = lane & 15;
    int o0 = blockIdx.y * 64, l0 = blockIdx.x * 64, b = blockIdx.z;
    if (tid < 64) sbias[tid] = obi[o0 + tid];
    f32x4 acc[4] = {};
    gemm_core64(won, aT + (size_t)b * TT * EE, EE, o0, l0, at, bt, acc);
    int l = l0 + w * 16 + l16;
    int mval = mask[(size_t)b * TT + l];
#pragma unroll
    for (int mt = 0; mt < 4; mt++)
#pragma unroll
        for (int reg = 0; reg < 4; reg++) {
            int o = o0 + mt * 16 + quad * 4 + reg;
            float v = mval ? (acc[mt][reg] + sbias[mt * 16 + quad * 4 + reg]) : 0.f;
            size_t off = ((size_t)b * EE + o) * TT + l;
            out[off] = v + x[off];
        }
}

// ---------------------------------------------------------------------------
// Pass A over COMPACT indices: l_s = sum_{t<Tc} exp2(q'.k) for compact s rows;
// then fused V LayerNorm on the compact column + 1/l_s fold -> vc.
// grid (16, NH, NB); blocks with s0 >= Sc exit.
// ---------------------------------------------------------------------------
__global__ __launch_bounds__(256) void attn_stats_mfma(
    const u16* __restrict__ qc, const u16* __restrict__ kc,
    const int* __restrict__ cntQ, const int* __restrict__ cntK,
    const float* __restrict__ gv, const float* __restrict__ bv,
    const u16* __restrict__ yv, u16* __restrict__ vc) {
    int s0 = blockIdx.x * 64, h = blockIdx.y, b = blockIdx.z;
    int Sc = cntK[b], Tc = cntQ[b];
    if (s0 >= Sc) return;
    __shared__ u16 kt[64][72];   // [s][d]
    __shared__ u16 qt[64][72];   // [t][d]
    __shared__ float lp[4][64];
    int tid = threadIdx.x;
    int w = tid >> 6, lane = tid & 63, quad = lane >> 4, l16 = lane & 15;
    int head = b * NH + h;
    const u16* kp = kc + (size_t)head * SS * DHH;
    const u16* qp = qc + (size_t)head * TT * DHH;
    int rA = tid >> 3, cA = (tid & 7) * 8;
#pragma unroll
    for (int m = 0; m < 2; m++)
        *(u16x8*)&kt[rA + 32 * m][cA] = *(const u16x8*)&kp[(size_t)(s0 + rA + 32 * m) * DHH + cA];
    u16x8 rq[2][2];
#pragma unroll
    for (int p = 0; p < 2; p++)
#pragma unroll
        for (int m = 0; m < 2; m++)
            rq[p][m] = *(const u16x8*)&qp[(size_t)(p * 64 + rA + 32 * m) * DHH + cA];
    float rl[4][4] = {};
    for (int t0 = 0; t0 < Tc; t0 += 128) {
#pragma unroll
        for (int half = 0; half < 2; half++) {
            int tb = t0 + half * 64;
            __syncthreads();
#pragma unroll
            for (int m = 0; m < 2; m++) *(u16x8*)&qt[rA + 32 * m][cA] = rq[half][m];
            __syncthreads();
            int tpre = tb + 128;
            if (tpre < TT) {
#pragma unroll
                for (int m = 0; m < 2; m++)
                    rq[half][m] = *(const u16x8*)&qp[(size_t)(tpre + rA + 32 * m) * DHH + cA];
            }
            int tcol = tb + w * 16 + l16;
            f32x4 acc[4] = {};
#pragma unroll
            for (int ks = 0; ks < 64; ks += 32) {
                short8 bf = *(const short8*)&qt[w * 16 + l16][ks + quad * 8];
#pragma unroll
                for (int mt = 0; mt < 4; mt++) {
                    short8 af = *(const short8*)&kt[mt * 16 + l16][ks + quad * 8];
                    acc[mt] = MFMA16(af, bf, acc[mt]);
                }
            }
            if (tcol < Tc) {
#pragma unroll
                for (int mt = 0; mt < 4; mt++)
#pragma unroll
                    for (int reg = 0; reg < 4; reg++)
                        rl[mt][reg] += EXP2(acc[mt][reg]);
            }
        }
    }
#pragma unroll
    for (int mt = 0; mt < 4; mt++) {
#pragma unroll
        for (int reg = 0; reg < 4; reg++) {
            float v = rl[mt][reg];
            v += __shfl_xor(v, 1); v += __shfl_xor(v, 2);
            v += __shfl_xor(v, 4); v += __shfl_xor(v, 8);
            if (l16 == 0) lp[w][mt * 16 + quad * 4 + reg] = v;
        }
    }
    __syncthreads();
    if (tid < 64 && s0 + tid < Sc) {
        int spos = s0 + tid;
        float lv = lp[0][tid] + lp[1][tid] + lp[2][tid] + lp[3][tid];
        float wsc = lv > 0.f ? (1.f / lv) : 0.f;
        const u16* vin = yv + ((size_t)b * EE + h * 64) * SS + spos;
        u16* vout = vc + ((size_t)b * EE + h * 64) * SS + spos;
        float sm = 0.f, s2 = 0.f;
        float vals[DHH];
#pragma unroll
        for (int d = 0; d < DHH; d++) {
            float v = bu2f(vin[(size_t)d * SS]);
            vals[d] = v; sm += v; s2 += v * v;
        }
        float mean = sm * (1.f / DHH);
        float var = s2 * (1.f / DHH) - mean * mean;
        float r = rsqrtf(var + EPSF);
#pragma unroll
        for (int d = 0; d < DHH; d++)
            vout[(size_t)d * SS] = f2bu(((vals[d] - mean) * r * gv[d] + bv[d]) * wsc);
    }
}

// ---------------------------------------------------------------------------
// Pass B over COMPACT indices: out[d][t] = sum_{s<Sc} V'[d][s]*exp2(q'.k).
// P rows past Sc zeroed; output rows scatter through tIdx. grid (16, NH, NB).
// ---------------------------------------------------------------------------
__global__ __launch_bounds__(256) void attn_pv_mfma(
    const u16* __restrict__ qc, const u16* __restrict__ kc, const u16* __restrict__ vc,
    const int* __restrict__ tIdx, const int* __restrict__ cntQ, const int* __restrict__ cntK,
    u16* __restrict__ aT) {
    int t0 = blockIdx.x * 64, h = blockIdx.y, b = blockIdx.z;
    int Tc = cntQ[b], Sc = cntK[b];
    if (t0 >= Tc) return;
    __shared__ u16 qt[64][72];   // [t][d]
    __shared__ u16 kt[64][72];   // [s][d]
    __shared__ u16 vt[64][72];   // [d][s]
    __shared__ u16 pt[64][72];   // [t][s] wave-local; reused for out tile
    int tid = threadIdx.x;
    int w = tid >> 6, lane = tid & 63, quad = lane >> 4, l16 = lane & 15;
    int head = b * NH + h;
    const u16* qp = qc + (size_t)head * TT * DHH;
    const u16* kp = kc + (size_t)head * SS * DHH;
    const u16* vp = vc + ((size_t)head * DHH) * SS;
    int rA = tid >> 3, cA = (tid & 7) * 8;
#pragma unroll
    for (int m = 0; m < 2; m++)
        *(u16x8*)&qt[rA + 32 * m][cA] = *(const u16x8*)&qp[(size_t)(t0 + rA + 32 * m) * DHH + cA];
    u16x8 rk[2][2], rv[2][2];
#pragma unroll
    for (int p = 0; p < 2; p++)
#pragma unroll
        for (int m = 0; m < 2; m++) {
            rk[p][m] = *(const u16x8*)&kp[(size_t)(p * 64 + rA + 32 * m) * DHH + cA];
            rv[p][m] = *(const u16x8*)&vp[(size_t)(rA + 32 * m) * SS + p * 64 + cA];
        }
    int tl = w * 16 + l16;

    f32x4 oacc[4] = {};
    for (int s0 = 0; s0 < Sc; s0 += 128) {
#pragma unroll
        for (int half = 0; half < 2; half++) {
            int sb = s0 + half * 64;
            if (sb >= Sc) break;
            __syncthreads();
#pragma unroll
            for (int m = 0; m < 2; m++) {
                *(u16x8*)&kt[rA + 32 * m][cA] = rk[half][m];
                *(u16x8*)&vt[rA + 32 * m][cA] = rv[half][m];
            }
            __syncthreads();
            int spre = sb + 128;
            if (spre < SS) {
#pragma unroll
                for (int m = 0; m < 2; m++) {
                    rk[half][m] = *(const u16x8*)&kp[(size_t)(spre + rA + 32 * m) * DHH + cA];
                    rv[half][m] = *(const u16x8*)&vp[(size_t)(rA + 32 * m) * SS + spre + cA];
                }
            }
            f32x4 acc[4] = {};
#pragma unroll
            for (int ks = 0; ks < 64; ks += 32) {
                short8 bf = *(const short8*)&qt[tl][ks + quad * 8];
#pragma unroll
                for (int mt = 0; mt < 4; mt++) {
                    short8 af = *(const short8*)&kt[mt * 16 + l16][ks + quad * 8];
                    acc[mt] = MFMA16(af, bf, acc[mt]);
                }
            }
#pragma unroll
            for (int mt = 0; mt < 4; mt++) {
                u16x4 pk;
#pragma unroll
                for (int reg = 0; reg < 4; reg++) {
                    int sl = mt * 16 + quad * 4 + reg;
                    pk[reg] = (sb + sl < Sc) ? f2bu(EXP2(acc[mt][reg])) : (u16)0;
                }
                *(u16x4*)&pt[tl][mt * 16 + quad * 4] = pk;
            }
#pragma unroll
            for (int ks = 0; ks < 64; ks += 32) {
                short8 bf = *(const short8*)&pt[tl][ks + quad * 8];
#pragma unroll
                for (int mt = 0; mt < 4; mt++) {
                    short8 af = *(const short8*)&vt[mt * 16 + l16][ks + quad * 8];
                    oacc[mt] = MFMA16(af, bf, oacc[mt]);
                }
            }
        }
    }
    __syncthreads();
#pragma unroll
    for (int mt = 0; mt < 4; mt++) {
        u16x4 pk;
#pragma unroll
        for (int reg = 0; reg < 4; reg++) pk[reg] = f2bu(oacc[mt][reg]);
        *(u16x4*)&pt[tl][mt * 16 + quad * 4] = pk;
    }
    __syncthreads();
    const int* ti = tIdx + (size_t)b * 1024;
#pragma unroll
    for (int i = 0; i < 2; i++) {
        int id = tid * 2 + i;
        int r = id >> 3, c = (id & 7) * 8;
        if (t0 + r < Tc) {
            int treal = ti[t0 + r];
            *(u16x8*)&aT[((size_t)b * TT + treal) * EE + h * 64 + c] =
                *(const u16x8*)&pt[r][c];
        }
    }
}

// ---------------------------------------------------------------------------
extern "C" void kernel_launch(void* const* d_in, const int* in_sizes, int n_in,
                              void* d_out, int out_size, void* d_ws, size_t ws_size,
                              hipStream_t stream) {
    const float* x        = (const float*)d_in[0];
    const float* ctx      = (const float*)d_in[1];
    const int*   mask     = (const int*)d_in[2];
    const int*   mask_ctx = (const int*)d_in[3];
    const float* qw  = (const float*)d_in[4];
    const float* qbi = (const float*)d_in[5];
    const float* kw  = (const float*)d_in[6];
    const float* kbi = (const float*)d_in[7];
    const float* vw  = (const float*)d_in[8];
    const float* vbi = (const float*)d_in[9];
    const float* ow  = (const float*)d_in[10];
    const float* obi = (const float*)d_in[11];
    const float* gq = (const float*)d_in[12];
    const float* bq = (const float*)d_in[13];
    const float* gk = (const float*)d_in[14];
    const float* bk = (const float*)d_in[15];
    const float* gv = (const float*)d_in[16];
    const float* bv = (const float*)d_in[17];

    // workspace carve (~63 MB)
    u16* p = (u16*)d_ws;
    u16* wqn = p; p += (size_t)EE * EE;
    u16* wkn = p; p += (size_t)EE * CCH;
    u16* wvn = p; p += (size_t)EE * CCH;
    u16* won = p; p += (size_t)EE * EE;
    u16* xc  = p; p += (size_t)NB * TT * EE;        // compact [b][pos][e]
    u16* cc  = p; p += (size_t)NB * SS * CCH;       // compact [b][pos][c]
    u16* yv  = p; p += (size_t)NB * EE * SS;        // v proj out, compact columns
    u16* qc  = p; p += (size_t)NB * NH * TT * DHH;  // compact q [bh][pos][d]
    u16* kc  = p; p += (size_t)NB * NH * SS * DHH;  // compact k [bh][pos][d]
    u16* vc  = p; p += (size_t)NB * EE * SS;        // compact V' [b][E][pos]
    u16* aT  = p; p += (size_t)NB * TT * EE;        // attn out [b][t][e]
    int* tIdx = (int*)p;
    int* sIdx = tIdx + NB * 1024;
    int* cntQ = sIdx + NB * 1024;
    int* cntK = cntQ + NB;

    // 1) weight standardization + mask scan (one dispatch)
    ws_norm_scan<<<dim3(1024, 5), 256, 0, stream>>>(
        qw, kw, vw, ow, wqn, wkn, wvn, won, mask, mask_ctx, tIdx, sIdx, cntQ, cntK);

    // 2) compacting transpose of x and ctx to [pos][i] bf16
    transpose2_compact<<<dim3(16, 28, NB), 256, 0, stream>>>(
        x, ctx, mask, mask_ctx, xc, cc);

    // 3) fused q/k/v projections over compact columns + LN epilogue (64x64)
    proj_qkv<<<dim3(16, 48, NB), 256, 0, stream>>>(
        wqn, wkn, wvn, xc, cc, qbi, kbi, vbi, cntQ, cntK,
        gq, bq, gk, bk, qc, kc, yv);

    // 4) softmax denominators on compact indices + fused V LN -> compact vc
    attn_stats_mfma<<<dim3(16, NH, NB), 256, 0, stream>>>(
        qc, kc, cntQ, cntK, gv, bv, yv, vc);

    // 5) PV on compact indices -> scatter into aT [b][t][e]
    attn_pv_mfma<<<dim3(16, NH, NB), 256, 0, stream>>>(
        qc, kc, vc, tIdx, cntQ, cntK, aT);

    // 6) o-proj (+mask +f32 residual) -> f32 d_out (64x64 tiles)
    proj_o<<<dim3(16, 16, NB), 256, 0, stream>>>(won, aT, obi, mask, x, (float*)d_out);
}

// Round 11
// 223.660 us; speedup vs baseline: 1.0774x; 1.0774x over previous
//
#include <hip/hip_runtime.h>

// Problem constants (B=4, T=S=1024, E=1024, CTX=768, H=16, DH=64)
#define NB 4
#define TT 1024
#define SS 1024
#define EE 1024
#define CCH 768
#define NH 16
#define DHH 64
#define EPSF 1e-5f
// SCALE = 1024 // (16**0.5) = 256.  Fold 1/256 * log2(e) into q so that
// exp(score/256) == exp2(q'.k) with a single v_exp_f32.
#define QSCALE (1.4426950408889634f / 256.0f)

typedef unsigned short u16;
typedef __attribute__((ext_vector_type(8))) short short8;       // MFMA A/B frag
typedef __attribute__((ext_vector_type(8))) unsigned short u16x8;
typedef __attribute__((ext_vector_type(4))) unsigned short u16x4;
typedef __attribute__((ext_vector_type(4))) float f32x4;        // MFMA C/D frag

__device__ __forceinline__ u16 f2bu(float f) {
    union { float f; unsigned u; } x; x.f = f;
    unsigned r = x.u + 0x7fffu + ((x.u >> 16) & 1u);
    return (u16)(r >> 16);
}
__device__ __forceinline__ float bu2f(u16 u) {
    union { unsigned u; float f; } x; x.u = ((unsigned)u) << 16; return x.f;
}

#if __has_builtin(__builtin_amdgcn_exp2f)
#define EXP2(x) __builtin_amdgcn_exp2f(x)
#else
#define EXP2(x) exp2f(x)
#endif

#define MFMA16(a, b, c) __builtin_amdgcn_mfma_f32_16x16x32_bf16((a), (b), (c), 0, 0, 0)

// prep block-range offsets
#define PREP_WS_END   4096                  // 4 mats x 1024 rows
#define PREP_SCAN_END (PREP_WS_END + 8)     // 2 masks x 4 batches
#define PREP_TR_END   (PREP_SCAN_END + 1792) // 16 x 28 x 4 transpose tiles
#define PREP_FILL_END (PREP_TR_END + 4096)  // 4 batches x 1024 rows fill

// ---------------------------------------------------------------------------
// PREP mega-kernel (all mutually independent prologue work, 1D grid):
//   [0,4096)      weight standardization -> bf16
//   [4096,4104)   mask prefix scan -> tIdx/sIdx + counts
//   [4104,5896)   compacting transpose x/ctx -> bf16 [b][pos][R]
//   [5896,9992)   masked-column residual fill: out[b,o,t] = x[b,o,t] (!mask[t])
// ---------------------------------------------------------------------------
__global__ __launch_bounds__(256) void prep(
    const float* __restrict__ qw, const float* __restrict__ kw,
    const float* __restrict__ vw, const float* __restrict__ ow,
    u16* __restrict__ wqn, u16* __restrict__ wkn,
    u16* __restrict__ wvn, u16* __restrict__ won,
    const float* __restrict__ x, const float* __restrict__ ctx,
    const int* __restrict__ mask, const int* __restrict__ mask_ctx,
    u16* __restrict__ xc, u16* __restrict__ cc,
    int* __restrict__ tIdx, int* __restrict__ sIdx,
    int* __restrict__ cntQ, int* __restrict__ cntK,
    float* __restrict__ outF) {
    __shared__ float tile[64][65];
    __shared__ int spos[64], smask[64], wtoti[4];
    __shared__ float sa[4], sb2[4], smean, srstd;
    int bid = blockIdx.x, tid = threadIdx.x;

    if (bid < PREP_WS_END) {
        int mat = bid >> 10, row = bid & 1023;
        const float* w = mat == 0 ? qw : (mat == 1 ? kw : (mat == 2 ? vw : ow));
        u16* wn = mat == 0 ? wqn : (mat == 1 ? wkn : (mat == 2 ? wvn : won));
        int I = (mat == 1 || mat == 2) ? CCH : EE;
        const float* wr = w + (size_t)row * I;
        float s = 0.f, s2 = 0.f;
        for (int i = tid; i < I; i += 256) { float v = wr[i]; s += v; s2 += v * v; }
#pragma unroll
        for (int off = 32; off > 0; off >>= 1) { s += __shfl_down(s, off); s2 += __shfl_down(s2, off); }
        int wid = tid >> 6;
        if ((tid & 63) == 0) { sa[wid] = s; sb2[wid] = s2; }
        __syncthreads();
        if (tid == 0) {
            float ts = sa[0] + sa[1] + sa[2] + sa[3];
            float ts2 = sb2[0] + sb2[1] + sb2[2] + sb2[3];
            float mean = ts / (float)I;
            float var = ts2 / (float)I - mean * mean;
            smean = mean; srstd = rsqrtf(var + EPSF);
        }
        __syncthreads();
        float mean = smean, r = srstd;
        u16* wo = wn + (size_t)row * I;
        for (int i = tid; i < I; i += 256) wo[i] = f2bu((wr[i] - mean) * r);
        return;
    }
    if (bid < PREP_SCAN_END) {
        int t = bid - PREP_WS_END;
        int which = t & 1, b = t >> 1;
        const int* m = (which ? mask_ctx : mask) + b * 1024;
        int* idx = (which ? sIdx : tIdx) + b * 1024;
        int* cnt = (which ? cntK : cntQ) + b;
        int base = tid * 4;
        int v[4]; int s = 0;
#pragma unroll
        for (int i = 0; i < 4; i++) { v[i] = m[base + i] ? 1 : 0; s += v[i]; }
        int lane = tid & 63, wid = tid >> 6;
        int inc = s;
#pragma unroll
        for (int off = 1; off < 64; off <<= 1) {
            int o = __shfl_up(inc, off);
            if (lane >= off) inc += o;
        }
        if (lane == 63) wtoti[wid] = inc;
        __syncthreads();
        int woff = 0;
        for (int i = 0; i < wid; i++) woff += wtoti[i];
        int p = woff + inc - s;
#pragma unroll
        for (int i = 0; i < 4; i++) {
            if (v[i]) idx[p] = base + i;
            p += v[i];
        }
        if (tid == 255) *cnt = p;
        return;
    }
    if (bid < PREP_TR_END) {
        int t = bid - PREP_SCAN_END;
        int xb = t & 15; int rem = t >> 4;
        int yy = rem % 28, b = rem / 28;
        int mat = yy < 16 ? 0 : 1;
        int r0 = (mat == 0 ? yy : yy - 16) * 64;
        int R = mat == 0 ? EE : CCH;
        const float* in = mat == 0 ? x : ctx;
        const int* m = (mat == 0 ? mask : mask_ctx) + (size_t)b * 1024;
        u16* out = mat == 0 ? xc : cc;
        int c0 = xb * 64;
        const float* ip = in + (size_t)b * R * 1024;
        u16* op = out + (size_t)b * R * 1024;
#pragma unroll
        for (int mm = 0; mm < 16; mm++) {
            int id = tid + 256 * mm; int r = id >> 6, c = id & 63;
            tile[r][c] = ip[(size_t)(r0 + r) * 1024 + c0 + c];
        }
        int base = tid * 4;
        int v[4]; int s = 0;
#pragma unroll
        for (int i = 0; i < 4; i++) { v[i] = m[base + i] ? 1 : 0; s += v[i]; }
        int lane = tid & 63, wid = tid >> 6;
        int inc = s;
#pragma unroll
        for (int off = 1; off < 64; off <<= 1) {
            int o = __shfl_up(inc, off);
            if (lane >= off) inc += o;
        }
        if (lane == 63) wtoti[wid] = inc;
        __syncthreads();
        int woff = 0;
        for (int i = 0; i < wid; i++) woff += wtoti[i];
        int p = woff + inc - s;
#pragma unroll
        for (int i = 0; i < 4; i++) {
            int g = base + i;
            if (g >= c0 && g < c0 + 64) { spos[g - c0] = p; smask[g - c0] = v[i]; }
            p += v[i];
        }
        __syncthreads();
#pragma unroll
        for (int mm = 0; mm < 16; mm++) {
            int id = tid + 256 * mm; int rr = id >> 6, cc2 = id & 63;
            if (smask[rr])
                op[(size_t)spos[rr] * R + r0 + cc2] = f2bu(tile[cc2][rr]);
        }
        return;
    }
    {   // masked residual fill
        int f = bid - PREP_TR_END;
        int b = f >> 10, o = f & 1023;
        const float* xr = x + ((size_t)b * EE + o) * TT;
        float* orow = outF + ((size_t)b * EE + o) * TT;
        const int* mrow = mask + (size_t)b * TT;
        int4 mv = ((const int4*)mrow)[tid];
        float4 xv = ((const float4*)xr)[tid];
        int t4 = tid * 4;
        if (!mv.x) orow[t4 + 0] = xv.x;
        if (!mv.y) orow[t4 + 1] = xv.y;
        if (!mv.z) orow[t4 + 2] = xv.z;
        if (!mv.w) orow[t4 + 3] = xv.w;
    }
}

// ---------------------------------------------------------------------------
// GEMM core: 128x64 tile, 4 waves, each a 64x32 quadrant (4x2 16x16x32 frags).
// Prefetch distance 2 (I % 128 == 0 holds for 1024 and 768).
// ---------------------------------------------------------------------------
__device__ __forceinline__ void gemm_core(
    const u16* __restrict__ A, const u16* __restrict__ Bp, int I,
    int o0, int l0, u16 (*at)[72], u16 (*bt)[72], f32x4 (&acc)[4][2]) {
    int tid = threadIdx.x;
    int w = tid >> 6, lane = tid & 63, quad = lane >> 4, l16 = lane & 15;
    int wm = w & 1, wn = w >> 1;
    int rA = tid >> 3, cA = (tid & 7) * 8;
    u16x8 ra[2][4], rb[2][2];
#pragma unroll
    for (int p = 0; p < 2; p++) {
        int kb = p * 64;
#pragma unroll
        for (int m = 0; m < 4; m++)
            ra[p][m] = *(const u16x8*)&A[(size_t)(o0 + rA + 32 * m) * I + kb + cA];
#pragma unroll
        for (int m = 0; m < 2; m++)
            rb[p][m] = *(const u16x8*)&Bp[(size_t)(l0 + rA + 32 * m) * I + kb + cA];
    }
    for (int k0 = 0; k0 < I; k0 += 128) {
#pragma unroll
        for (int half = 0; half < 2; half++) {
            __syncthreads();
#pragma unroll
            for (int m = 0; m < 4; m++) *(u16x8*)&at[rA + 32 * m][cA] = ra[half][m];
#pragma unroll
            for (int m = 0; m < 2; m++) *(u16x8*)&bt[rA + 32 * m][cA] = rb[half][m];
            __syncthreads();
            int kpre = k0 + half * 64 + 128;
            if (kpre < I) {
#pragma unroll
                for (int m = 0; m < 4; m++)
                    ra[half][m] = *(const u16x8*)&A[(size_t)(o0 + rA + 32 * m) * I + kpre + cA];
#pragma unroll
                for (int m = 0; m < 2; m++)
                    rb[half][m] = *(const u16x8*)&Bp[(size_t)(l0 + rA + 32 * m) * I + kpre + cA];
            }
#pragma unroll
            for (int ks = 0; ks < 64; ks += 32) {
                short8 af[4], bf[2];
#pragma unroll
                for (int i = 0; i < 4; i++)
                    af[i] = *(const short8*)&at[wm * 64 + i * 16 + l16][ks + quad * 8];
#pragma unroll
                for (int j = 0; j < 2; j++)
                    bf[j] = *(const short8*)&bt[wn * 32 + j * 16 + l16][ks + quad * 8];
#pragma unroll
                for (int mt = 0; mt < 4; mt++)
#pragma unroll
                    for (int nt = 0; nt < 2; nt++)
                        acc[mt][nt] = MFMA16(af[mt], bf[nt], acc[mt][nt]);
            }
        }
    }
}

// 64x64-tile core (used by compact proj_o; 4x1 frags per wave).
__device__ __forceinline__ void gemm_core64(
    const u16* __restrict__ A, const u16* __restrict__ Bp, int I,
    int o0, int l0, u16 (*at)[72], u16 (*bt)[72], f32x4 (&acc)[4]) {
    int tid = threadIdx.x;
    int w = tid >> 6, lane = tid & 63, quad = lane >> 4, l16 = lane & 15;
    int rA = tid >> 3, cA = (tid & 7) * 8;
    u16x8 ra[2][2], rb[2][2];
#pragma unroll
    for (int p = 0; p < 2; p++) {
        int kb = p * 64;
#pragma unroll
        for (int m = 0; m < 2; m++) {
            ra[p][m] = *(const u16x8*)&A[(size_t)(o0 + rA + 32 * m) * I + kb + cA];
            rb[p][m] = *(const u16x8*)&Bp[(size_t)(l0 + rA + 32 * m) * I + kb + cA];
        }
    }
    for (int k0 = 0; k0 < I; k0 += 128) {
#pragma unroll
        for (int half = 0; half < 2; half++) {
            __syncthreads();
#pragma unroll
            for (int m = 0; m < 2; m++) {
                *(u16x8*)&at[rA + 32 * m][cA] = ra[half][m];
                *(u16x8*)&bt[rA + 32 * m][cA] = rb[half][m];
            }
            __syncthreads();
            int kpre = k0 + half * 64 + 128;
            if (kpre < I) {
#pragma unroll
                for (int m = 0; m < 2; m++) {
                    ra[half][m] = *(const u16x8*)&A[(size_t)(o0 + rA + 32 * m) * I + kpre + cA];
                    rb[half][m] = *(const u16x8*)&Bp[(size_t)(l0 + rA + 32 * m) * I + kpre + cA];
                }
            }
#pragma unroll
            for (int ks = 0; ks < 64; ks += 32) {
                short8 bf = *(const short8*)&bt[w * 16 + l16][ks + quad * 8];
#pragma unroll
                for (int mt = 0; mt < 4; mt++) {
                    short8 af = *(const short8*)&at[mt * 16 + l16][ks + quad * 8];
                    acc[mt] = MFMA16(af, bf, acc[mt]);
                }
            }
        }
    }
}

// ---------------------------------------------------------------------------
// Fused q/k/v projections over COMPACT columns + per-head LN epilogue (q,k).
// 128x64 tiles. grid (24, 16, NB) with x = (mat, o-tile): since gx=24 and
// gy-stride 24 = 0 mod 8, linear_id % 8 = x % 8 -> all l-tiles of one weight
// tile land on one XCD (L2 reuse of the weight tile).
// ---------------------------------------------------------------------------
__global__ __launch_bounds__(256) void proj_qkv(
    const u16* __restrict__ wq, const u16* __restrict__ wk, const u16* __restrict__ wv,
    const u16* __restrict__ xc, const u16* __restrict__ cc,
    const float* __restrict__ qb, const float* __restrict__ kb, const float* __restrict__ vbi,
    const int* __restrict__ cntQ, const int* __restrict__ cntK,
    const float* __restrict__ gq, const float* __restrict__ bq,
    const float* __restrict__ gk, const float* __restrict__ bk,
    u16* __restrict__ qc, u16* __restrict__ kc, u16* __restrict__ yv) {
    int mat = blockIdx.x >> 3;
    int o0 = (blockIdx.x & 7) * 128;
    int l0 = blockIdx.y * 64;
    int b = blockIdx.z;
    int limit = (mat == 0) ? cntQ[b] : cntK[b];
    if (l0 >= limit) return;
    __shared__ u16 at[128][72];
    __shared__ u16 bt[64][72];
    __shared__ float sg[64], sbe[64], sbias[128];
    int tid = threadIdx.x;
    int w = tid >> 6, lane = tid & 63, quad = lane >> 4, l16 = lane & 15;
    int wm = w & 1, wn = w >> 1;
    const u16* A = mat == 0 ? wq : (mat == 1 ? wk : wv);
    const u16* BT = mat == 0 ? xc : cc;
    const float* bias = mat == 0 ? qb : (mat == 1 ? kb : vbi);
    int I = mat == 0 ? EE : CCH;
    if (mat < 2 && tid < 64) {
        sg[tid] = (mat == 0 ? gq : gk)[tid];
        sbe[tid] = (mat == 0 ? bq : bk)[tid];
    }
    if (tid < 128) sbias[tid] = bias[o0 + tid];

    f32x4 acc[4][2] = {};
    gemm_core(A, BT + (size_t)b * 1024 * I, I, o0, l0, at, bt, acc);

    if (mat < 2) {
        u16* outT = mat == 0 ? qc : kc;
        float scale = mat == 0 ? QSCALE : 1.0f;
        int h = (o0 >> 6) + wm;
        int bh = b * NH + h;
#pragma unroll
        for (int nt = 0; nt < 2; nt++) {
            int l = l0 + wn * 32 + nt * 16 + l16;
            float vbuf[16];
            float s = 0.f;
#pragma unroll
            for (int mt = 0; mt < 4; mt++)
#pragma unroll
                for (int reg = 0; reg < 4; reg++) {
                    float v = acc[mt][nt][reg] + sbias[wm * 64 + mt * 16 + quad * 4 + reg];
                    vbuf[mt * 4 + reg] = v; s += v;
                }
            s += __shfl_xor(s, 16); s += __shfl_xor(s, 32);
            float mean = s * (1.f / 64);
            float s2 = 0.f;
#pragma unroll
            for (int i = 0; i < 16; i++) { float dv = vbuf[i] - mean; s2 += dv * dv; }
            s2 += __shfl_xor(s2, 16); s2 += __shfl_xor(s2, 32);
            float r = rsqrtf(s2 * (1.f / 64) + EPSF);
            if (l < limit) {
                u16* op = outT + ((size_t)bh * 1024 + l) * 64;
#pragma unroll
                for (int mt = 0; mt < 4; mt++) {
                    u16x4 pk;
#pragma unroll
                    for (int reg = 0; reg < 4; reg++) {
                        int d = mt * 16 + quad * 4 + reg;
                        pk[reg] = f2bu(((vbuf[mt * 4 + reg] - mean) * r * sg[d] + sbe[d]) * scale);
                    }
                    *(u16x4*)&op[mt * 16 + quad * 4] = pk;
                }
            }
        }
    } else {
#pragma unroll
        for (int nt = 0; nt < 2; nt++) {
            int l = l0 + wn * 32 + nt * 16 + l16;
            if (l < limit) {
#pragma unroll
                for (int mt = 0; mt < 4; mt++)
#pragma unroll
                    for (int reg = 0; reg < 4; reg++) {
                        int o = o0 + wm * 64 + mt * 16 + quad * 4 + reg;
                        float v = acc[mt][nt][reg] + sbias[wm * 64 + mt * 16 + quad * 4 + reg];
                        yv[((size_t)b * EE + o) * 1024 + l] = f2bu(v);
                    }
            }
        }
    }
}

// ---------------------------------------------------------------------------
// Pass A over COMPACT indices: l_s = sum_{t<Tc} exp2(q'.k) for compact s rows;
// then fused V LayerNorm on the compact column + 1/l_s fold -> vc.
// grid (16, NH, NB); blocks with s0 >= Sc exit.
// ---------------------------------------------------------------------------
__global__ __launch_bounds__(256) void attn_stats_mfma(
    const u16* __restrict__ qc, const u16* __restrict__ kc,
    const int* __restrict__ cntQ, const int* __restrict__ cntK,
    const float* __restrict__ gv, const float* __restrict__ bv,
    const u16* __restrict__ yv, u16* __restrict__ vc) {
    int s0 = blockIdx.x * 64, h = blockIdx.y, b = blockIdx.z;
    int Sc = cntK[b], Tc = cntQ[b];
    if (s0 >= Sc) return;
    __shared__ u16 kt[64][72];   // [s][d]
    __shared__ u16 qt[64][72];   // [t][d]
    __shared__ float lp[4][64];
    int tid = threadIdx.x;
    int w = tid >> 6, lane = tid & 63, quad = lane >> 4, l16 = lane & 15;
    int head = b * NH + h;
    const u16* kp = kc + (size_t)head * SS * DHH;
    const u16* qp = qc + (size_t)head * TT * DHH;
    int rA = tid >> 3, cA = (tid & 7) * 8;
#pragma unroll
    for (int m = 0; m < 2; m++)
        *(u16x8*)&kt[rA + 32 * m][cA] = *(const u16x8*)&kp[(size_t)(s0 + rA + 32 * m) * DHH + cA];
    u16x8 rq[2][2];
#pragma unroll
    for (int p = 0; p < 2; p++)
#pragma unroll
        for (int m = 0; m < 2; m++)
            rq[p][m] = *(const u16x8*)&qp[(size_t)(p * 64 + rA + 32 * m) * DHH + cA];
    float rl[4][4] = {};
    for (int t0 = 0; t0 < Tc; t0 += 128) {
#pragma unroll
        for (int half = 0; half < 2; half++) {
            int tb = t0 + half * 64;
            __syncthreads();
#pragma unroll
            for (int m = 0; m < 2; m++) *(u16x8*)&qt[rA + 32 * m][cA] = rq[half][m];
            __syncthreads();
            int tpre = tb + 128;
            if (tpre < TT) {
#pragma unroll
                for (int m = 0; m < 2; m++)
                    rq[half][m] = *(const u16x8*)&qp[(size_t)(tpre + rA + 32 * m) * DHH + cA];
            }
            int tcol = tb + w * 16 + l16;
            f32x4 acc[4] = {};
#pragma unroll
            for (int ks = 0; ks < 64; ks += 32) {
                short8 bf = *(const short8*)&qt[w * 16 + l16][ks + quad * 8];
#pragma unroll
                for (int mt = 0; mt < 4; mt++) {
                    short8 af = *(const short8*)&kt[mt * 16 + l16][ks + quad * 8];
                    acc[mt] = MFMA16(af, bf, acc[mt]);
                }
            }
            if (tcol < Tc) {
#pragma unroll
                for (int mt = 0; mt < 4; mt++)
#pragma unroll
                    for (int reg = 0; reg < 4; reg++)
                        rl[mt][reg] += EXP2(acc[mt][reg]);
            }
        }
    }
#pragma unroll
    for (int mt = 0; mt < 4; mt++) {
#pragma unroll
        for (int reg = 0; reg < 4; reg++) {
            float v = rl[mt][reg];
            v += __shfl_xor(v, 1); v += __shfl_xor(v, 2);
            v += __shfl_xor(v, 4); v += __shfl_xor(v, 8);
            if (l16 == 0) lp[w][mt * 16 + quad * 4 + reg] = v;
        }
    }
    __syncthreads();
    if (tid < 64 && s0 + tid < Sc) {
        int spos = s0 + tid;
        float lv = lp[0][tid] + lp[1][tid] + lp[2][tid] + lp[3][tid];
        float wsc = lv > 0.f ? (1.f / lv) : 0.f;
        const u16* vin = yv + ((size_t)b * EE + h * 64) * SS + spos;
        u16* vout = vc + ((size_t)b * EE + h * 64) * SS + spos;
        float sm = 0.f, s2 = 0.f;
        float vals[DHH];
#pragma unroll
        for (int d = 0; d < DHH; d++) {
            float v = bu2f(vin[(size_t)d * SS]);
            vals[d] = v; sm += v; s2 += v * v;
        }
        float mean = sm * (1.f / DHH);
        float var = s2 * (1.f / DHH) - mean * mean;
        float r = rsqrtf(var + EPSF);
#pragma unroll
        for (int d = 0; d < DHH; d++)
            vout[(size_t)d * SS] = f2bu(((vals[d] - mean) * r * gv[d] + bv[d]) * wsc);
    }
}

// ---------------------------------------------------------------------------
// Pass B over COMPACT indices: out[d][t] = sum_{s<Sc} V'[d][s]*exp2(q'.k).
// Output written DENSE into compact ac [b][pos][e] (no scatter).
// grid (16, NH, NB).
// ---------------------------------------------------------------------------
__global__ __launch_bounds__(256) void attn_pv_mfma(
    const u16* __restrict__ qc, const u16* __restrict__ kc, const u16* __restrict__ vc,
    const int* __restrict__ cntQ, const int* __restrict__ cntK,
    u16* __restrict__ ac) {
    int t0 = blockIdx.x * 64, h = blockIdx.y, b = blockIdx.z;
    int Tc = cntQ[b], Sc = cntK[b];
    if (t0 >= Tc) return;
    __shared__ u16 qt[64][72];   // [t][d]
    __shared__ u16 kt[64][72];   // [s][d]
    __shared__ u16 vt[64][72];   // [d][s]
    __shared__ u16 pt[64][72];   // [t][s] wave-local; reused for out tile
    int tid = threadIdx.x;
    int w = tid >> 6, lane = tid & 63, quad = lane >> 4, l16 = lane & 15;
    int head = b * NH + h;
    const u16* qp = qc + (size_t)head * TT * DHH;
    const u16* kp = kc + (size_t)head * SS * DHH;
    const u16* vp = vc + ((size_t)head * DHH) * SS;
    int rA = tid >> 3, cA = (tid & 7) * 8;
#pragma unroll
    for (int m = 0; m < 2; m++)
        *(u16x8*)&qt[rA + 32 * m][cA] = *(const u16x8*)&qp[(size_t)(t0 + rA + 32 * m) * DHH + cA];
    u16x8 rk[2][2], rv[2][2];
#pragma unroll
    for (int p = 0; p < 2; p++)
#pragma unroll
        for (int m = 0; m < 2; m++) {
            rk[p][m] = *(const u16x8*)&kp[(size_t)(p * 64 + rA + 32 * m) * DHH + cA];
            rv[p][m] = *(const u16x8*)&vp[(size_t)(rA + 32 * m) * SS + p * 64 + cA];
        }
    int tl = w * 16 + l16;

    f32x4 oacc[4] = {};
    for (int s0 = 0; s0 < Sc; s0 += 128) {
#pragma unroll
        for (int half = 0; half < 2; half++) {
            int sb = s0 + half * 64;
            if (sb >= Sc) break;
            __syncthreads();
#pragma unroll
            for (int m = 0; m < 2; m++) {
                *(u16x8*)&kt[rA + 32 * m][cA] = rk[half][m];
                *(u16x8*)&vt[rA + 32 * m][cA] = rv[half][m];
            }
            __syncthreads();
            int spre = sb + 128;
            if (spre < SS) {
#pragma unroll
                for (int m = 0; m < 2; m++) {
                    rk[half][m] = *(const u16x8*)&kp[(size_t)(spre + rA + 32 * m) * DHH + cA];
                    rv[half][m] = *(const u16x8*)&vp[(size_t)(rA + 32 * m) * SS + spre + cA];
                }
            }
            f32x4 acc[4] = {};
#pragma unroll
            for (int ks = 0; ks < 64; ks += 32) {
                short8 bf = *(const short8*)&qt[tl][ks + quad * 8];
#pragma unroll
                for (int mt = 0; mt < 4; mt++) {
                    short8 af = *(const short8*)&kt[mt * 16 + l16][ks + quad * 8];
                    acc[mt] = MFMA16(af, bf, acc[mt]);
                }
            }
#pragma unroll
            for (int mt = 0; mt < 4; mt++) {
                u16x4 pk;
#pragma unroll
                for (int reg = 0; reg < 4; reg++) {
                    int sl = mt * 16 + quad * 4 + reg;
                    pk[reg] = (sb + sl < Sc) ? f2bu(EXP2(acc[mt][reg])) : (u16)0;
                }
                *(u16x4*)&pt[tl][mt * 16 + quad * 4] = pk;
            }
#pragma unroll
            for (int ks = 0; ks < 64; ks += 32) {
                short8 bf = *(const short8*)&pt[tl][ks + quad * 8];
#pragma unroll
                for (int mt = 0; mt < 4; mt++) {
                    short8 af = *(const short8*)&vt[mt * 16 + l16][ks + quad * 8];
                    oacc[mt] = MFMA16(af, bf, oacc[mt]);
                }
            }
        }
    }
    __syncthreads();
#pragma unroll
    for (int mt = 0; mt < 4; mt++) {
        u16x4 pk;
#pragma unroll
        for (int reg = 0; reg < 4; reg++) pk[reg] = f2bu(oacc[mt][reg]);
        *(u16x4*)&pt[tl][mt * 16 + quad * 4] = pk;
    }
    __syncthreads();
#pragma unroll
    for (int i = 0; i < 2; i++) {
        int id = tid * 2 + i;
        int r = id >> 3, c = (id & 7) * 8;
        if (t0 + r < Tc)
            *(u16x8*)&ac[((size_t)b * TT + t0 + r) * EE + h * 64 + c] =
                *(const u16x8*)&pt[r][c];
    }
}

// ---------------------------------------------------------------------------
// Output projection over COMPACT columns (+bias +f32 residual) -> f32,
// scattered through tIdx. Masked columns were pre-filled by prep.
// 64x64 tiles; grid (16, 16, NB): x = o-tile (16 % 8 == 0 -> XCD-stable),
// y = compact l-tile (exit past Tc).
// ---------------------------------------------------------------------------
__global__ __launch_bounds__(256) void proj_o(
    const u16* __restrict__ won, const u16* __restrict__ ac,
    const float* __restrict__ obi, const int* __restrict__ tIdx,
    const int* __restrict__ cntQ, const float* __restrict__ x,
    float* __restrict__ out) {
    int o0 = blockIdx.x * 64, l0 = blockIdx.y * 64, b = blockIdx.z;
    int Tc = cntQ[b];
    if (l0 >= Tc) return;
    __shared__ u16 at[64][72];
    __shared__ u16 bt[64][72];
    __shared__ float sbias[64];
    __shared__ int stre[64];
    int tid = threadIdx.x;
    int w = tid >> 6, lane = tid & 63, quad = lane >> 4, l16 = lane & 15;
    if (tid < 64) {
        sbias[tid] = obi[o0 + tid];
        stre[tid] = tIdx[(size_t)b * 1024 + l0 + tid];
    }
    f32x4 acc[4] = {};
    gemm_core64(won, ac + (size_t)b * TT * EE, EE, o0, l0, at, bt, acc);
    int l = l0 + w * 16 + l16;
    if (l < Tc) {
        int treal = stre[w * 16 + l16];
#pragma unroll
        for (int mt = 0; mt < 4; mt++)
#pragma unroll
            for (int reg = 0; reg < 4; reg++) {
                int o = o0 + mt * 16 + quad * 4 + reg;
                size_t off = ((size_t)b * EE + o) * TT + treal;
                out[off] = acc[mt][reg] + sbias[mt * 16 + quad * 4 + reg] + x[off];
            }
    }
}

// ---------------------------------------------------------------------------
extern "C" void kernel_launch(void* const* d_in, const int* in_sizes, int n_in,
                              void* d_out, int out_size, void* d_ws, size_t ws_size,
                              hipStream_t stream) {
    const float* x        = (const float*)d_in[0];
    const float* ctx      = (const float*)d_in[1];
    const int*   mask     = (const int*)d_in[2];
    const int*   mask_ctx = (const int*)d_in[3];
    const float* qw  = (const float*)d_in[4];
    const float* qbi = (const float*)d_in[5];
    const float* kw  = (const float*)d_in[6];
    const float* kbi = (const float*)d_in[7];
    const float* vw  = (const float*)d_in[8];
    const float* vbi = (const float*)d_in[9];
    const float* ow  = (const float*)d_in[10];
    const float* obi = (const float*)d_in[11];
    const float* gq = (const float*)d_in[12];
    const float* bq = (const float*)d_in[13];
    const float* gk = (const float*)d_in[14];
    const float* bk = (const float*)d_in[15];
    const float* gv = (const float*)d_in[16];
    const float* bv = (const float*)d_in[17];

    // workspace carve (~63 MB)
    u16* p = (u16*)d_ws;
    u16* wqn = p; p += (size_t)EE * EE;
    u16* wkn = p; p += (size_t)EE * CCH;
    u16* wvn = p; p += (size_t)EE * CCH;
    u16* won = p; p += (size_t)EE * EE;
    u16* xc  = p; p += (size_t)NB * TT * EE;        // compact [b][pos][e]
    u16* cc  = p; p += (size_t)NB * SS * CCH;       // compact [b][pos][c]
    u16* yv  = p; p += (size_t)NB * EE * SS;        // v proj out, compact columns
    u16* qc  = p; p += (size_t)NB * NH * TT * DHH;  // compact q [bh][pos][d]
    u16* kc  = p; p += (size_t)NB * NH * SS * DHH;  // compact k [bh][pos][d]
    u16* vc  = p; p += (size_t)NB * EE * SS;        // compact V' [b][E][pos]
    u16* ac  = p; p += (size_t)NB * TT * EE;        // attn out compact [b][pos][e]
    int* tIdx = (int*)p;
    int* sIdx = tIdx + NB * 1024;
    int* cntQ = sIdx + NB * 1024;
    int* cntK = cntQ + NB;

    // 1) prep: WS-norm + mask scan + compacting transpose + masked resid fill
    prep<<<PREP_FILL_END, 256, 0, stream>>>(
        qw, kw, vw, ow, wqn, wkn, wvn, won, x, ctx, mask, mask_ctx,
        xc, cc, tIdx, sIdx, cntQ, cntK, (float*)d_out);

    // 2) fused q/k/v projections over compact columns + LN epilogue (128x64)
    proj_qkv<<<dim3(24, 16, NB), 256, 0, stream>>>(
        wqn, wkn, wvn, xc, cc, qbi, kbi, vbi, cntQ, cntK,
        gq, bq, gk, bk, qc, kc, yv);

    // 3) softmax denominators on compact indices + fused V LN -> compact vc
    attn_stats_mfma<<<dim3(16, NH, NB), 256, 0, stream>>>(
        qc, kc, cntQ, cntK, gv, bv, yv, vc);

    // 4) PV on compact indices -> dense compact ac
    attn_pv_mfma<<<dim3(16, NH, NB), 256, 0, stream>>>(
        qc, kc, vc, cntQ, cntK, ac);

    // 5) o-proj over compact columns (+bias +resid), scatter via tIdx
    proj_o<<<dim3(16, 16, NB), 256, 0, stream>>>(
        won, ac, obi, tIdx, cntQ, x, (float*)d_out);
}